// Round 7
// baseline (574.184 us; speedup 1.0000x reference)
//
#include <hip/hip_runtime.h>

#define NPTS 500000
#define NVOX 50000
#define NBLK 196   // ceil(NVOX/256)

typedef unsigned short u16;
typedef unsigned int u32;
typedef __attribute__((ext_vector_type(8))) short short8;
typedef __attribute__((ext_vector_type(4))) float floatx4;
typedef __attribute__((ext_vector_type(16))) float floatx16;
typedef __attribute__((ext_vector_type(4))) unsigned int uintx4;
typedef __attribute__((ext_vector_type(2))) unsigned int uintx2;

__device__ __forceinline__ u16 f2bf(float f) {
    u32 u = __float_as_uint(f);
    u = u + 0x7fffu + ((u >> 16) & 1u);   // RNE
    return (u16)(u >> 16);
}

#if defined(__has_builtin)
#if __has_builtin(__builtin_amdgcn_cvt_pk_bf16_f32)
#define HAVE_PKBF 1
#endif
#endif

// pack two fp32 -> bf16x2 (a low, b high), RNE
__device__ __forceinline__ u32 pkbf(float a, float b) {
#ifdef HAVE_PKBF
    typedef __attribute__((ext_vector_type(2))) __bf16 bf16x2;
    bf16x2 v = __builtin_amdgcn_cvt_pk_bf16_f32(a, b);
    u32 r; __builtin_memcpy(&r, &v, 4);
    return r;
#else
    return (u32)f2bf(a) | ((u32)f2bf(b) << 16);
#endif
}

// ---- K0: weight transforms ----
// 16x16x32 B-operand pack (used by k_gemm_relu / k_pointfeat):
//   Wf[((kk*4+q)*N + n)*8 + j] = W[(kk*32+q*8+j)*N + n]
__device__ __forceinline__ void wswz(const float* __restrict__ W, u16* __restrict__ Wf, int N, int t) {
    int k = t / N, n = t - k * N;
    int kk = k >> 5, q = (k >> 3) & 3, j = k & 7;
    Wf[((size_t)((kk * 4 + q) * N + n) << 3) + j] = f2bf(W[t]);
}

// 32x32x16 A-operand pack of W^T (lane l holds A[m=l&31][k=(l>>5)*8+j]):
//   Wf[((kk*2+h)*N + n)*8 + j] = W[(kk*16+h*8+j)*N + n]
__device__ __forceinline__ void wswz32(const float* __restrict__ W, u16* __restrict__ Wf, int N, int t) {
    int k = t / N, n = t - k * N;
    int kk = k >> 4, h = (k >> 3) & 1, j = k & 7;
    Wf[((size_t)((kk * 2 + h) * N + n) << 3) + j] = f2bf(W[t]);
}

__global__ __launch_bounds__(256) void k_wprep(
    const float* __restrict__ w3, const float* __restrict__ w4,
    const float* __restrict__ wv1, const float* __restrict__ wv2,
    const float* __restrict__ w2x, const float* __restrict__ w2r,
    const float* __restrict__ wax, const float* __restrict__ war,
    u16* __restrict__ w3f, u16* __restrict__ w4f, u16* __restrict__ wv1f, u16* __restrict__ wv2f,
    u16* __restrict__ wcatf, u16* __restrict__ wattf)
{
    int t = blockIdx.x * 256 + threadIdx.x;
    if (t < 65536) { wswz32(w3, w3f, 256, t); return; }  t -= 65536;
    if (t < 65536) { wswz32(w4, w4f, 256, t); return; }  t -= 65536;
    if (t < 65536) { wswz(wv2, wv2f, 256, t); return; } t -= 65536;
    if (t < 16384) { wswz(wv1, wv1f, 128, t); return; } t -= 16384;
    if (t < 8192) {   // block-diag [[w2x,0],[0,w2r]] (128x64)
        int k = t >> 6, n = t & 63;
        float v;
        if (k < 64) v = (n < 32) ? w2x[k * 32 + n] : 0.f;
        else        v = (n >= 32) ? w2r[(k - 64) * 32 + (n - 32)] : 0.f;
        int kk = k >> 5, q = (k >> 3) & 3, j = k & 7;
        wcatf[((size_t)((kk * 4 + q) * 64 + n) << 3) + j] = f2bf(v);
        return;
    }
    t -= 8192;
    if (t < 4096) {   // [wax | war] (64x64)
        int k = t >> 6, n = t & 63;
        float v = (n < 32) ? wax[k * 32 + n] : war[k * 32 + (n - 32)];
        int kk = k >> 5, q = (k >> 3) & 3, j = k & 7;
        wattf[((size_t)((kk * 4 + q) * 64 + n) << 3) + j] = f2bf(v);
    }
}

// ---- CSR build: histogram -> 3-phase parallel scan -> scatter (sptid + sorted vid) ----
__global__ void k_hist(const int* __restrict__ idx, int* __restrict__ hcnt) {
    int i = blockIdx.x * 256 + threadIdx.x;
    if (i < NPTS) atomicAdd(&hcnt[idx[i]], 1);
}

__global__ __launch_bounds__(256) void k_scan1(const int* __restrict__ hcnt, int* __restrict__ bsum) {
    __shared__ int wsum[4];
    int t = threadIdx.x;
    int i = blockIdx.x * 256 + t;
    int c = (i < NVOX) ? hcnt[i] : 0;
    #pragma unroll
    for (int d = 32; d >= 1; d >>= 1) c += __shfl_xor(c, d, 64);
    if ((t & 63) == 0) wsum[t >> 6] = c;
    __syncthreads();
    if (t == 0) bsum[blockIdx.x] = wsum[0] + wsum[1] + wsum[2] + wsum[3];
}

__global__ __launch_bounds__(256) void k_scan2(const int* __restrict__ bsum, int* __restrict__ boff) {
    __shared__ int wsum[4];
    int t = threadIdx.x, lane = t & 63, w = t >> 6;
    int c = (t < NBLK) ? bsum[t] : 0;
    int v = c;
    #pragma unroll
    for (int d = 1; d < 64; d <<= 1) {
        int o = __shfl_up(v, d, 64);
        if (lane >= d) v += o;
    }
    if (lane == 63) wsum[w] = v;
    __syncthreads();
    int wo = 0;
    #pragma unroll
    for (int k = 0; k < 4; k++) if (k < w) wo += wsum[k];
    if (t < NBLK) boff[t] = wo + v - c;
}

__global__ __launch_bounds__(256) void k_scan3(const int* __restrict__ hcnt, const int* __restrict__ boff,
                                               int* __restrict__ cur) {
    __shared__ int wsum[4];
    int t = threadIdx.x, lane = t & 63, w = t >> 6;
    int i = blockIdx.x * 256 + t;
    int c = (i < NVOX) ? hcnt[i] : 0;
    int v = c;
    #pragma unroll
    for (int d = 1; d < 64; d <<= 1) {
        int o = __shfl_up(v, d, 64);
        if (lane >= d) v += o;
    }
    if (lane == 63) wsum[w] = v;
    __syncthreads();
    int wo = 0;
    #pragma unroll
    for (int k = 0; k < 4; k++) if (k < w) wo += wsum[k];
    if (i < NVOX) cur[i] = boff[blockIdx.x] + wo + v - c;
}

__global__ void k_scatter(const int* __restrict__ idx, int* __restrict__ cur,
                          int* __restrict__ sptid, int* __restrict__ svid) {
    int i = blockIdx.x * 256 + threadIdx.x;
    if (i < NPTS) {
        int v = idx[i];
        int pos = atomicAdd(&cur[v], 1);
        sptid[pos] = i;
        svid[pos] = v;
    }
}

// ---- K1: sorted-order MFMA point encoder + fused pf2 segment-max -> voxmax (fp32) ----
// 128 points/block, 8 waves (4 col-stripes x 2 row-halves). comb reuses hbuf cols 0..63.
__global__ __launch_bounds__(512) void k_pointfeat(
    const float* __restrict__ inp, const int* __restrict__ sptid, const int* __restrict__ svid,
    const float* __restrict__ w1x, const float* __restrict__ b1x,
    const float* __restrict__ w1r, const float* __restrict__ b1r,
    const u16* __restrict__ wcatf, const float* __restrict__ b2x, const float* __restrict__ b2r,
    const u16* __restrict__ wattf, const float* __restrict__ bax, const float* __restrict__ bar,
    u16* __restrict__ pf2s, float* __restrict__ voxmax)
{
    __shared__ u16 hbuf[128 * 136];  // h tile (128x128 +8 pad); comb reuses cols 0..63; pf2 out-tile
    __shared__ float wl[512];        // w1x(192) b1x(64) w1r(192) b1r(64)
    __shared__ int lvid[128];
    int t = threadIdx.x;
    int i0 = blockIdx.x * 128;
    int mcnt = NPTS - i0; if (mcnt > 128) mcnt = 128;
    {
        float v;
        if (t < 192)      v = w1x[t];
        else if (t < 256) v = b1x[t - 192];
        else if (t < 448) v = w1r[t - 256];
        else              v = b1r[t - 448];
        wl[t] = v;
    }
    if (t < 128) lvid[t] = (t < mcnt) ? svid[i0 + t] : -1;
    __syncthreads();
    {   // layer 1: K=3 on VALU, 4 threads/point each produce 16 h_x + 16 h_r cols
        int m = t >> 2, c = t & 3;
        float x0 = 0, x1 = 0, x2 = 0, r0 = 0, r1 = 0, r2 = 0;
        if (m < mcnt) {
            const float* p = inp + (size_t)sptid[i0 + m] * 6;
            x0 = p[0]; x1 = p[1]; x2 = p[2]; r0 = p[3]; r1 = p[4]; r2 = p[5];
        }
        u16* hb = &hbuf[m * 136 + c * 16];
        #pragma unroll
        for (int jp = 0; jp < 8; jp++) {
            int c0 = c * 16 + 2 * jp, c1 = c0 + 1;
            float hx0 = fmaxf(wl[192 + c0] + x0 * wl[c0] + x1 * wl[64 + c0] + x2 * wl[128 + c0], 0.f);
            float hx1 = fmaxf(wl[192 + c1] + x0 * wl[c1] + x1 * wl[64 + c1] + x2 * wl[128 + c1], 0.f);
            float hr0 = fmaxf(wl[448 + c0] + r0 * wl[256 + c0] + r1 * wl[320 + c0] + r2 * wl[384 + c0], 0.f);
            float hr1 = fmaxf(wl[448 + c1] + r0 * wl[256 + c1] + r1 * wl[320 + c1] + r2 * wl[384 + c1], 0.f);
            *(u32*)(hb + 2 * jp)      = pkbf(hx0, hx1);
            *(u32*)(hb + 64 + 2 * jp) = pkbf(hr0, hr1);
        }
    }
    __syncthreads();
    int wave = t >> 6, l = t & 63, q = l >> 4, lm = l & 15;
    int n = (wave & 3) * 16 + lm;    // output col (0..63)
    int rh = (wave >> 2) * 64;       // row half base
    // GEMM1: comb(128x64) = h(128x128) @ wcat(128x64)
    floatx4 acc[4];
    #pragma unroll
    for (int a = 0; a < 4; a++) acc[a] = (floatx4){0.f, 0.f, 0.f, 0.f};
    #pragma unroll
    for (int kk = 0; kk < 4; kk++) {
        short8 bfrag = *(const short8*)&wcatf[(size_t)((kk * 4 + q) * 64 + n) << 3];
        #pragma unroll
        for (int tm = 0; tm < 4; tm++) {
            short8 afrag = *(const short8*)&hbuf[(rh + tm * 16 + lm) * 136 + kk * 32 + q * 8];
            acc[tm] = __builtin_amdgcn_mfma_f32_16x16x32_bf16(afrag, bfrag, acc[tm], 0, 0, 0);
        }
    }
    float bv = (n < 32) ? b2x[n] : b2r[n - 32];
    float comb_keep[4][4];
    #pragma unroll
    for (int tm = 0; tm < 4; tm++)
        #pragma unroll
        for (int r = 0; r < 4; r++)
            comb_keep[tm][r] = fmaxf(acc[tm][r] + bv, 0.f);
    __syncthreads();   // all waves done reading h before comb overwrites cols 0..63
    #pragma unroll
    for (int tm = 0; tm < 4; tm++)
        #pragma unroll
        for (int r = 0; r < 4; r++) {
            int m = rh + tm * 16 + q * 4 + r;     // C/D: row = quad*4+reg, col = lane&15
            hbuf[m * 136 + n] = f2bf(comb_keep[tm][r]);
        }
    __syncthreads();
    // GEMM2: att(128x64) = comb @ watt; same C-layout as comb -> register-local gating
    floatx4 acc2[4];
    #pragma unroll
    for (int a = 0; a < 4; a++) acc2[a] = (floatx4){0.f, 0.f, 0.f, 0.f};
    #pragma unroll
    for (int kk = 0; kk < 2; kk++) {
        short8 bfrag = *(const short8*)&wattf[(size_t)((kk * 4 + q) * 64 + n) << 3];
        #pragma unroll
        for (int tm = 0; tm < 4; tm++) {
            short8 afrag = *(const short8*)&hbuf[(rh + tm * 16 + lm) * 136 + kk * 32 + q * 8];
            acc2[tm] = __builtin_amdgcn_mfma_f32_16x16x32_bf16(afrag, bfrag, acc2[tm], 0, 0, 0);
        }
    }
    __syncthreads();   // all waves done reading comb before gating overwrites
    float bv2 = (n < 32) ? bax[n] : bar[n - 32];
    int pp = (n < 32) ? n : 32 + n;   // pf2 col of plain value; gated at pp+32
    #pragma unroll
    for (int tm = 0; tm < 4; tm++)
        #pragma unroll
        for (int r = 0; r < 4; r++) {
            float att = acc2[tm][r] + bv2;
            float sg = 1.f / (1.f + __expf(-att));
            float plain = comb_keep[tm][r];
            float gated = plain * sg;
            int m = rh + tm * 16 + q * 4 + r;
            hbuf[m * 136 + pp] = f2bf(plain);
            hbuf[m * 136 + pp + 32] = f2bf(gated);
        }
    __syncthreads();
    {   // coalesced pf2s store (sorted rows): 4 threads/row x 64B
        int row = t >> 2, seg = t & 3;
        if (row < mcnt) {
            const u16* src = &hbuf[row * 136 + seg * 32];
            u16* dst = pf2s + (size_t)(i0 + row) * 128 + seg * 32;
            *(uintx4*)dst = *(const uintx4*)src;
            *(uintx4*)(dst + 8) = *(const uintx4*)(src + 8);
        }
    }
    {   // fused segment-max over sorted vid runs -> voxmax fp32 (values >= 0, int cmp)
        int c2 = t & 63;           // u32 col-pair (cols 2c2, 2c2+1) of 128
        int h = t >> 6;            // row sixteenth
        int r0 = h * 16;
        int r1 = r0 + 16; if (r1 > mcnt) r1 = mcnt;
        u32 mlo = 0, mhi = 0;
        int pvid = -1;
        for (int r = r0; r < r1; r++) {
            int vid = lvid[r];
            if (vid != pvid) {
                if (pvid >= 0) {
                    int* addr = (int*)(voxmax + (size_t)pvid * 128 + 2 * c2);
                    if (mlo) atomicMax(addr, (int)(mlo << 16));
                    if (mhi) atomicMax(addr + 1, (int)(mhi << 16));
                }
                pvid = vid; mlo = 0; mhi = 0;
            }
            u32 u = *(const u32*)&hbuf[r * 136 + 2 * c2];
            u32 lo = u & 0xffffu, hi = u >> 16;
            mlo = lo > mlo ? lo : mlo;
            mhi = hi > mhi ? hi : mhi;
        }
        if (pvid >= 0) {
            int* addr = (int*)(voxmax + (size_t)pvid * 128 + 2 * c2);
            if (mlo) atomicMax(addr, (int)(mlo << 16));
            if (mhi) atomicMax(addr + 1, (int)(mhi << 16));
        }
    }
}

// ---- generic MFMA GEMM: out = relu(A @ W + bias); A fp32 or bf16; W pre-swizzled bf16 ----
template<int K, int N, bool ABF16, bool OUT_BF16>
__global__ __launch_bounds__(256) void k_gemm_relu(
    const void* __restrict__ Ap, const u16* __restrict__ Wf,
    const float* __restrict__ bias, void* __restrict__ outp, int M)
{
    constexpr int STRIDE = K + 8;
    constexpr int TN = N / 64;
    constexpr int KSTEPS = K / 32;
    constexpr int CW = K / 4;
    __shared__ u16 lds[64 * STRIDE];
    int i0 = blockIdx.x * 64;
    int mcnt = M - i0; if (mcnt > 64) mcnt = 64;
    int t = threadIdx.x;
    {
        int row = t >> 2, cseg = t & 3;
        u16* dst = &lds[row * STRIDE + cseg * CW];
        if (row < mcnt) {
            if (ABF16) {
                const u16* src = (const u16*)Ap + (size_t)(i0 + row) * K + cseg * CW;
                #pragma unroll
                for (int c = 0; c < CW / 8; c++)
                    *(uintx4*)(dst + c * 8) = *(const uintx4*)(src + c * 8);
            } else {
                const float* src = (const float*)Ap + (size_t)(i0 + row) * K + cseg * CW;
                #pragma unroll
                for (int c = 0; c < CW / 8; c++) {
                    float4 v0 = *(const float4*)(src + c * 8);
                    float4 v1 = *(const float4*)(src + c * 8 + 4);
                    uintx4 rr = {pkbf(v0.x, v0.y), pkbf(v0.z, v0.w), pkbf(v1.x, v1.y), pkbf(v1.z, v1.w)};
                    *(uintx4*)(dst + c * 8) = rr;
                }
            }
        } else {
            uintx4 z = {0, 0, 0, 0};
            #pragma unroll
            for (int c = 0; c < CW / 8; c++) *(uintx4*)(dst + c * 8) = z;
        }
    }
    __syncthreads();
    int wave = t >> 6, l = t & 63;
    int q = l >> 4, lm = l & 15;
    int wn0 = wave * (N / 4);
    floatx4 acc[4][TN];
    #pragma unroll
    for (int a = 0; a < 4; a++)
        #pragma unroll
        for (int b = 0; b < TN; b++) acc[a][b] = (floatx4){0.f, 0.f, 0.f, 0.f};
    #pragma unroll
    for (int kk = 0; kk < KSTEPS; kk++) {
        short8 afrag[4], bfrag[TN];
        #pragma unroll
        for (int tm = 0; tm < 4; tm++)
            afrag[tm] = *(const short8*)&lds[(tm * 16 + lm) * STRIDE + kk * 32 + q * 8];
        #pragma unroll
        for (int tn = 0; tn < TN; tn++)
            bfrag[tn] = *(const short8*)&Wf[(size_t)((kk * 4 + q) * N + wn0 + tn * 16 + lm) * 8];
        #pragma unroll
        for (int tm = 0; tm < 4; tm++)
            #pragma unroll
            for (int tn = 0; tn < TN; tn++)
                acc[tm][tn] = __builtin_amdgcn_mfma_f32_16x16x32_bf16(afrag[tm], bfrag[tn], acc[tm][tn], 0, 0, 0);
    }
    #pragma unroll
    for (int tm = 0; tm < 4; tm++)
        #pragma unroll
        for (int tn = 0; tn < TN; tn++) {
            int n = wn0 + tn * 16 + lm;
            float bv = bias[n];
            #pragma unroll
            for (int r = 0; r < 4; r++) {
                int m = tm * 16 + q * 4 + r;
                if (m < mcnt) {
                    float v = fmaxf(acc[tm][tn][r] + bv, 0.f);
                    if (OUT_BF16) ((u16*)outp)[(size_t)(i0 + m) * N + n] = f2bf(v);
                    else          ((float*)outp)[(size_t)(i0 + m) * N + n] = v;
                }
            }
        }
}

// ---- K3: sorted fused point MLP, 32x32x16 MFMA, weights as A-operand, XOR-swizzled LDS ----
// 256 threads, 4 waves; wave = 128 out-ch x 32 points. Act tile [point][ch] with 16B chunk c
// of row p stored at chunk c ^ ((p>>3)&3). 1 LDS B-frag per kk per wave (duplication = 2).
__global__ __launch_bounds__(256) void k_pointmlp(
    const u16* __restrict__ voxf, const u16* __restrict__ pf2s, const int* __restrict__ svid,
    const u16* __restrict__ w3f, const float* __restrict__ b3,
    const u16* __restrict__ w4f, const float* __restrict__ b4,
    float* __restrict__ vox2)
{
    constexpr int STRIDE = 264;
    __shared__ u16 lds[64 * STRIDE];
    __shared__ int lvid[64];
    __shared__ float bl[512];   // b3(256) | b4(256)
    int i0 = blockIdx.x * 64;
    int mcnt = NPTS - i0; if (mcnt > 64) mcnt = 64;
    int t = threadIdx.x;
    if (t < 64) lvid[t] = (t < mcnt) ? svid[i0 + t] : -1;
    for (int s = t; s < 512; s += 256) bl[s] = (s < 256) ? b3[s] : b4[s - 256];
    {   // staging: 4 threads/row, 64 bf16 (8 chunks of 16B) each, XOR-swizzled dst
        int row = t >> 2, cseg = t & 3;
        int sig = (row >> 3) & 3;
        if (row < mcnt) {
            const u16* src;
            if (cseg < 2) src = voxf + (size_t)svid[i0 + row] * 128 + cseg * 64;     // pg half
            else          src = pf2s + (size_t)(i0 + row) * 128 + (cseg - 2) * 64;   // pf2 half
            #pragma unroll
            for (int c = 0; c < 8; c++) {
                int chunk = cseg * 8 + c;
                *(uintx4*)&lds[row * STRIDE + (chunk ^ sig) * 8] = *(const uintx4*)(src + c * 8);
            }
        } else {
            uintx4 z = {0, 0, 0, 0};
            #pragma unroll
            for (int c = 0; c < 8; c++) {
                int chunk = cseg * 8 + c;
                *(uintx4*)&lds[row * STRIDE + (chunk ^ sig) * 8] = z;
            }
        }
    }
    __syncthreads();
    int wave = t >> 6, l = t & 63;
    int am = l & 31, hh = l >> 5;
    int cg = wave & 1;            // out-ch half: 0 -> ch 0..127, 1 -> 128..255
    int pg = wave >> 1;           // point half: rows pg*32..+32
    int pbase = pg * 32;
    int p = pbase + am;           // this lane's B-column point row
    int sigp = (p >> 3) & 3;
    int chb = cg * 128;
    // GEMM1: H^T[ch][pt] = sum_k W3[k][ch] * act[pt][k]
    floatx16 acc[4];
    #pragma unroll
    for (int a = 0; a < 4; a++)
        #pragma unroll
        for (int e = 0; e < 16; e++) acc[a][e] = 0.f;
    #pragma unroll
    for (int kk = 0; kk < 16; kk++) {
        short8 bfrag = *(const short8*)&lds[p * STRIDE + (((kk * 2 + hh) ^ sigp) << 3)];
        #pragma unroll
        for (int tm = 0; tm < 4; tm++) {
            short8 wfrag = *(const short8*)&w3f[(size_t)((kk * 2 + hh) * 256 + chb + tm * 32 + am) * 8];
            acc[tm] = __builtin_amdgcn_mfma_f32_32x32x16_bf16(wfrag, bfrag, acc[tm], 0, 0, 0);
        }
    }
    __syncthreads();   // all bfrag reads of act done before H overwrites tile
    // H = relu(acc + b3) -> LDS [point][ch], swizzled, b64 writes
    // C/D 32x32: col(=pt)=lane&31, row(=ch)= (reg&3) + 8*(reg>>2) + 4*(lane>>5)
    #pragma unroll
    for (int tm = 0; tm < 4; tm++) {
        int chb2 = chb + tm * 32;
        #pragma unroll
        for (int rg = 0; rg < 4; rg++) {
            int ch0 = chb2 + 8 * rg + 4 * hh;
            float4 bq = *(const float4*)&bl[ch0];
            u32 lo = pkbf(fmaxf(acc[tm][4 * rg + 0] + bq.x, 0.f), fmaxf(acc[tm][4 * rg + 1] + bq.y, 0.f));
            u32 hi = pkbf(fmaxf(acc[tm][4 * rg + 2] + bq.z, 0.f), fmaxf(acc[tm][4 * rg + 3] + bq.w, 0.f));
            int chunk = (chb2 >> 3) + rg;
            *(uintx2*)&lds[p * STRIDE + ((chunk ^ sigp) << 3) + 4 * hh] = (uintx2){lo, hi};
        }
    }
    __syncthreads();
    // GEMM2: pf5^T = W4^T @ H^T
    floatx16 acc2[4];
    #pragma unroll
    for (int a = 0; a < 4; a++)
        #pragma unroll
        for (int e = 0; e < 16; e++) acc2[a][e] = 0.f;
    #pragma unroll
    for (int kk = 0; kk < 16; kk++) {
        short8 bfrag = *(const short8*)&lds[p * STRIDE + (((kk * 2 + hh) ^ sigp) << 3)];
        #pragma unroll
        for (int tm = 0; tm < 4; tm++) {
            short8 wfrag = *(const short8*)&w4f[(size_t)((kk * 2 + hh) * 256 + chb + tm * 32 + am) * 8];
            acc2[tm] = __builtin_amdgcn_mfma_f32_32x32x16_bf16(wfrag, bfrag, acc2[tm], 0, 0, 0);
        }
    }
    __syncthreads();   // all H reads done before pf5 overwrites
    // pf5 = relu(acc2 + b4) -> LDS, swizzled
    #pragma unroll
    for (int tm = 0; tm < 4; tm++) {
        int chb2 = chb + tm * 32;
        #pragma unroll
        for (int rg = 0; rg < 4; rg++) {
            int ch0 = chb2 + 8 * rg + 4 * hh;
            float4 bq = *(const float4*)&bl[256 + ch0];
            u32 lo = pkbf(fmaxf(acc2[tm][4 * rg + 0] + bq.x, 0.f), fmaxf(acc2[tm][4 * rg + 1] + bq.y, 0.f));
            u32 hi = pkbf(fmaxf(acc2[tm][4 * rg + 2] + bq.z, 0.f), fmaxf(acc2[tm][4 * rg + 3] + bq.w, 0.f));
            int chunk = (chb2 >> 3) + rg;
            *(uintx2*)&lds[p * STRIDE + ((chunk ^ sigp) << 3) + 4 * hh] = (uintx2){lo, hi};
        }
    }
    __syncthreads();
    // segmented max over sorted vid runs: thread owns u32 col-pair x 32 rows (swizzled reads)
    {
        int c2 = t & 127;          // u32 column (cols 2c2, 2c2+1)
        int h = t >> 7;            // row half
        int r0 = h * 32;
        int r1 = r0 + 32; if (r1 > mcnt) r1 = mcnt;
        int chunk = c2 >> 2, off = (2 * c2) & 7;
        u32 mlo = 0, mhi = 0;
        int pvid = -1;
        for (int r = r0; r < r1; r++) {
            int vid = lvid[r];
            if (vid != pvid) {
                if (pvid >= 0) {
                    int* addr = (int*)(vox2 + (size_t)pvid * 256 + 2 * c2);
                    if (mlo) atomicMax(addr, (int)(mlo << 16));
                    if (mhi) atomicMax(addr + 1, (int)(mhi << 16));
                }
                pvid = vid; mlo = 0; mhi = 0;
            }
            int sig = (r >> 3) & 3;
            u32 u = *(const u32*)&lds[r * STRIDE + ((chunk ^ sig) << 3) + off];
            u32 lo = u & 0xffffu, hi = u >> 16;
            mlo = lo > mlo ? lo : mlo;
            mhi = hi > mhi ? hi : mhi;
        }
        if (pvid >= 0) {
            int* addr = (int*)(vox2 + (size_t)pvid * 256 + 2 * c2);
            if (mlo) atomicMax(addr, (int)(mlo << 16));
            if (mhi) atomicMax(addr + 1, (int)(mhi << 16));
        }
    }
}

extern "C" void kernel_launch(void* const* d_in, const int* in_sizes, int n_in,
                              void* d_out, int out_size, void* d_ws, size_t ws_size,
                              hipStream_t stream) {
    const float* inp = (const float*)d_in[0];
    const int*   idx = (const int*)d_in[1];
    const float* w1x = (const float*)d_in[3];  const float* b1x = (const float*)d_in[4];
    const float* w2x = (const float*)d_in[5];  const float* b2x = (const float*)d_in[6];
    const float* w1r = (const float*)d_in[7];  const float* b1r = (const float*)d_in[8];
    const float* w2r = (const float*)d_in[9];  const float* b2r = (const float*)d_in[10];
    const float* wax = (const float*)d_in[11]; const float* bax = (const float*)d_in[12];
    const float* war = (const float*)d_in[13]; const float* bar = (const float*)d_in[14];
    const float* wv1 = (const float*)d_in[15]; const float* bv1 = (const float*)d_in[16];
    const float* w3  = (const float*)d_in[17]; const float* b3  = (const float*)d_in[18];
    const float* w4  = (const float*)d_in[19]; const float* b4  = (const float*)d_in[20];
    const float* wv2 = (const float*)d_in[21]; const float* bv2 = (const float*)d_in[22];
    float* out = (float*)d_out;

    char* ws = (char*)d_ws;
    u16*   pf2s   = (u16*)ws;   ws += (size_t)NPTS * 128 * sizeof(u16);   // 128 MB (sorted rows)
    float* voxmax = (float*)ws; ws += (size_t)NVOX * 128 * sizeof(float); // 25.6 MB
    u16*   voxf   = (u16*)ws;   ws += (size_t)NVOX * 128 * sizeof(u16);   // 12.8 MB
    float* vox2   = (float*)ws; ws += (size_t)NVOX * 256 * sizeof(float); // 51.2 MB
    u16*   w3f    = (u16*)ws;   ws += 65536 * sizeof(u16);
    u16*   w4f    = (u16*)ws;   ws += 65536 * sizeof(u16);
    u16*   wv1f   = (u16*)ws;   ws += 16384 * sizeof(u16);
    u16*   wv2f   = (u16*)ws;   ws += 65536 * sizeof(u16);
    u16*   wcatf  = (u16*)ws;   ws += 8192 * sizeof(u16);
    u16*   wattf  = (u16*)ws;   ws += 4096 * sizeof(u16);
    int*   hcnt   = (int*)ws;   ws += (size_t)NVOX * sizeof(int);
    int*   cur    = (int*)ws;   ws += (size_t)NVOX * sizeof(int);
    int*   bsum   = (int*)ws;   ws += (size_t)NBLK * sizeof(int);
    int*   boff   = (int*)ws;   ws += (size_t)NBLK * sizeof(int);
    int*   sptid  = (int*)ws;   ws += (size_t)NPTS * sizeof(int);
    int*   svid   = (int*)ws;   ws += (size_t)NPTS * sizeof(int);

    hipMemsetAsync(hcnt, 0, (size_t)NVOX * sizeof(int), stream);
    hipMemsetAsync(voxmax, 0, (size_t)NVOX * 128 * sizeof(float), stream);
    hipMemsetAsync(vox2, 0, (size_t)NVOX * 256 * sizeof(float), stream);

    k_wprep<<<880, 256, 0, stream>>>(w3, w4, wv1, wv2, w2x, w2r, wax, war,
                                     w3f, w4f, wv1f, wv2f, wcatf, wattf);

    k_hist<<<(NPTS + 255) / 256, 256, 0, stream>>>(idx, hcnt);
    k_scan1<<<NBLK, 256, 0, stream>>>(hcnt, bsum);
    k_scan2<<<1, 256, 0, stream>>>(bsum, boff);
    k_scan3<<<NBLK, 256, 0, stream>>>(hcnt, boff, cur);
    k_scatter<<<(NPTS + 255) / 256, 256, 0, stream>>>(idx, cur, sptid, svid);

    k_pointfeat<<<(NPTS + 127) / 128, 512, 0, stream>>>(
        inp, sptid, svid, w1x, b1x, w1r, b1r, wcatf, b2x, b2r, wattf, bax, bar, pf2s, voxmax);

    k_gemm_relu<128, 128, false, true><<<(NVOX + 63) / 64, 256, 0, stream>>>(
        (const void*)voxmax, wv1f, bv1, (void*)voxf, NVOX);

    k_pointmlp<<<(NPTS + 63) / 64, 256, 0, stream>>>(
        voxf, pf2s, svid, w3f, b3, w4f, b4, vox2);

    k_gemm_relu<256, 256, false, false><<<(NVOX + 63) / 64, 256, 0, stream>>>(
        (const void*)vox2, wv2f, bv2, (void*)out, NVOX);
}

// Round 8
// 545.925 us; speedup vs baseline: 1.0518x; 1.0518x over previous
//
#include <hip/hip_runtime.h>

#define NPTS 500000
#define NVOX 50000
#define NBLK 196   // ceil(NVOX/256)

typedef unsigned short u16;
typedef unsigned int u32;
typedef __attribute__((ext_vector_type(8))) short short8;
typedef __attribute__((ext_vector_type(4))) float floatx4;
typedef __attribute__((ext_vector_type(4))) unsigned int uintx4;
typedef __attribute__((ext_vector_type(2))) unsigned int uintx2;

__device__ __forceinline__ u16 f2bf(float f) {
    u32 u = __float_as_uint(f);
    u = u + 0x7fffu + ((u >> 16) & 1u);   // RNE
    return (u16)(u >> 16);
}

#if defined(__has_builtin)
#if __has_builtin(__builtin_amdgcn_cvt_pk_bf16_f32)
#define HAVE_PKBF 1
#endif
#endif

// pack two fp32 -> bf16x2 (a low, b high), RNE
__device__ __forceinline__ u32 pkbf(float a, float b) {
#ifdef HAVE_PKBF
    typedef __attribute__((ext_vector_type(2))) __bf16 bf16x2;
    bf16x2 v = __builtin_amdgcn_cvt_pk_bf16_f32(a, b);
    u32 r; __builtin_memcpy(&r, &v, 4);
    return r;
#else
    return (u32)f2bf(a) | ((u32)f2bf(b) << 16);
#endif
}

// ---- K0: all weight transforms fused. 16x16x32 pack (B-operand of W / A-operand of W^T):
//   Wf[((kk*4+q)*N + n)*8 + j] = W[(kk*32+q*8+j)*N + n]
__device__ __forceinline__ void wswz(const float* __restrict__ W, u16* __restrict__ Wf, int N, int t) {
    int k = t / N, n = t - k * N;
    int kk = k >> 5, q = (k >> 3) & 3, j = k & 7;
    Wf[((size_t)((kk * 4 + q) * N + n) << 3) + j] = f2bf(W[t]);
}

__global__ __launch_bounds__(256) void k_wprep(
    const float* __restrict__ w3, const float* __restrict__ w4,
    const float* __restrict__ wv1, const float* __restrict__ wv2,
    const float* __restrict__ w2x, const float* __restrict__ w2r,
    const float* __restrict__ wax, const float* __restrict__ war,
    const float* __restrict__ w1x, const float* __restrict__ b1x,
    const float* __restrict__ w1r, const float* __restrict__ b1r,
    u16* __restrict__ w3f, u16* __restrict__ w4f, u16* __restrict__ wv1f, u16* __restrict__ wv2f,
    u16* __restrict__ wcatf, u16* __restrict__ wattf, u16* __restrict__ w1ef)
{
    int t = blockIdx.x * 256 + threadIdx.x;
    if (t < 65536) { wswz(w3, w3f, 256, t); return; }  t -= 65536;
    if (t < 65536) { wswz(w4, w4f, 256, t); return; }  t -= 65536;
    if (t < 65536) { wswz(wv2, wv2f, 256, t); return; } t -= 65536;
    if (t < 16384) { wswz(wv1, wv1f, 128, t); return; } t -= 16384;
    if (t < 8192) {   // block-diag [[w2x,0],[0,w2r]] (128x64)
        int k = t >> 6, n = t & 63;
        float v;
        if (k < 64) v = (n < 32) ? w2x[k * 32 + n] : 0.f;
        else        v = (n >= 32) ? w2r[(k - 64) * 32 + (n - 32)] : 0.f;
        int kk = k >> 5, q = (k >> 3) & 3, j = k & 7;
        wcatf[((size_t)((kk * 4 + q) * 64 + n) << 3) + j] = f2bf(v);
        return;
    }
    t -= 8192;
    if (t < 4096) {   // [wax | war] (64x64)
        int k = t >> 6, n = t & 63;
        float v = (n < 32) ? wax[k * 32 + n] : war[k * 32 + (n - 32)];
        int kk = k >> 5, q = (k >> 3) & 3, j = k & 7;
        wattf[((size_t)((kk * 4 + q) * 64 + n) << 3) + j] = f2bf(v);
        return;
    }
    t -= 4096;
    if (t < 4096) {   // W1e (32x128): rows 0-2 w1x, 3 b1x (cols 0..63); 4-6 w1r, 7 b1r (cols 64..127)
        int k = t >> 7, n = t & 127;
        float v = 0.f;
        if (n < 64) {
            if (k < 3)       v = w1x[k * 64 + n];
            else if (k == 3) v = b1x[n];
        } else {
            if (k >= 4 && k < 7) v = w1r[(k - 4) * 64 + (n - 64)];
            else if (k == 7)     v = b1r[n - 64];
        }
        int q = (k >> 3) & 3, j = k & 7;   // kk = 0
        w1ef[((size_t)(q * 128 + n) << 3) + j] = f2bf(v);
    }
}

// ---- CSR build: histogram -> 3-phase parallel scan -> scatter (sptid + sorted vid) ----
__global__ void k_hist(const int* __restrict__ idx, int* __restrict__ hcnt) {
    int i = blockIdx.x * 256 + threadIdx.x;
    if (i < NPTS) atomicAdd(&hcnt[idx[i]], 1);
}

__global__ __launch_bounds__(256) void k_scan1(const int* __restrict__ hcnt, int* __restrict__ bsum) {
    __shared__ int wsum[4];
    int t = threadIdx.x;
    int i = blockIdx.x * 256 + t;
    int c = (i < NVOX) ? hcnt[i] : 0;
    #pragma unroll
    for (int d = 32; d >= 1; d >>= 1) c += __shfl_xor(c, d, 64);
    if ((t & 63) == 0) wsum[t >> 6] = c;
    __syncthreads();
    if (t == 0) bsum[blockIdx.x] = wsum[0] + wsum[1] + wsum[2] + wsum[3];
}

__global__ __launch_bounds__(256) void k_scan2(const int* __restrict__ bsum, int* __restrict__ boff) {
    __shared__ int wsum[4];
    int t = threadIdx.x, lane = t & 63, w = t >> 6;
    int c = (t < NBLK) ? bsum[t] : 0;
    int v = c;
    #pragma unroll
    for (int d = 1; d < 64; d <<= 1) {
        int o = __shfl_up(v, d, 64);
        if (lane >= d) v += o;
    }
    if (lane == 63) wsum[w] = v;
    __syncthreads();
    int wo = 0;
    #pragma unroll
    for (int k = 0; k < 4; k++) if (k < w) wo += wsum[k];
    if (t < NBLK) boff[t] = wo + v - c;
}

__global__ __launch_bounds__(256) void k_scan3(const int* __restrict__ hcnt, const int* __restrict__ boff,
                                               int* __restrict__ cur) {
    __shared__ int wsum[4];
    int t = threadIdx.x, lane = t & 63, w = t >> 6;
    int i = blockIdx.x * 256 + t;
    int c = (i < NVOX) ? hcnt[i] : 0;
    int v = c;
    #pragma unroll
    for (int d = 1; d < 64; d <<= 1) {
        int o = __shfl_up(v, d, 64);
        if (lane >= d) v += o;
    }
    if (lane == 63) wsum[w] = v;
    __syncthreads();
    int wo = 0;
    #pragma unroll
    for (int k = 0; k < 4; k++) if (k < w) wo += wsum[k];
    if (i < NVOX) cur[i] = boff[blockIdx.x] + wo + v - c;
}

__global__ void k_scatter(const int* __restrict__ idx, int* __restrict__ cur,
                          int* __restrict__ sptid, int* __restrict__ svid) {
    int i = blockIdx.x * 256 + threadIdx.x;
    if (i < NPTS) {
        int v = idx[i];
        int pos = atomicAdd(&cur[v], 1);
        sptid[pos] = i;
        svid[pos] = v;
    }
}

// ---- K1: sorted-order MFMA point encoder (layer-1 via K=32 MFMA) + fused segment-max ----
__global__ __launch_bounds__(256) void k_pointfeat(
    const float* __restrict__ inp, const int* __restrict__ sptid, const int* __restrict__ svid,
    const u16* __restrict__ w1ef,
    const u16* __restrict__ wcatf, const float* __restrict__ b2x, const float* __restrict__ b2r,
    const u16* __restrict__ wattf, const float* __restrict__ bax, const float* __restrict__ bar,
    u16* __restrict__ pf2s, float* __restrict__ voxmax)
{
    __shared__ u16 hbuf[64 * 136];   // h tile (64x128 +8 pad); reused for pf2 out-tile
    __shared__ u16 cbuf[64 * 72];    // comb tile (64x64 +8 pad)
    __shared__ u16 abuf[64 * 40];    // layer-1 A tile (64x32 +8 pad)
    __shared__ int lvid[64];
    int t = threadIdx.x;
    int i0 = blockIdx.x * 64;
    int mcnt = NPTS - i0; if (mcnt > 64) mcnt = 64;
    if (t < 64) lvid[t] = (t < mcnt) ? svid[i0 + t] : -1;
    {   // stage A rows: [x0,x1,x2,1, r0,r1,r2,1, 0 x24], 4 threads/point
        int m = t >> 2, c = t & 3;
        u16* ab = &abuf[m * 40];
        bool act = (m < mcnt);
        if (c < 3) {
            float2 v = {0.f, 0.f};
            if (act) v = *(const float2*)(inp + (size_t)sptid[i0 + m] * 6 + 2 * c);
            if (c == 0)      { ab[0] = f2bf(v.x); ab[1] = f2bf(v.y); }
            else if (c == 1) { ab[2] = f2bf(v.x); ab[4] = f2bf(v.y); }
            else             { ab[5] = f2bf(v.x); ab[6] = f2bf(v.y); }
        } else {
            u16 one = act ? (u16)0x3F80 : (u16)0;
            ab[3] = one; ab[7] = one;
        }
        #pragma unroll
        for (int z = 0; z < 3; z++) *(u32*)&ab[8 + 6 * c + 2 * z] = 0;   // zero cols 8..31
    }
    __syncthreads();
    int wave = t >> 6, l = t & 63, q = l >> 4, lm = l & 15;
    // GEMM_h: h(64x128) = A(64x32) @ W1e(32x128); wave covers 32 h-cols
    {
        floatx4 hacc[4][2];
        #pragma unroll
        for (int a = 0; a < 4; a++)
            #pragma unroll
            for (int b = 0; b < 2; b++) hacc[a][b] = (floatx4){0.f, 0.f, 0.f, 0.f};
        short8 bfrag[2], afrag[4];
        #pragma unroll
        for (int tn = 0; tn < 2; tn++)
            bfrag[tn] = *(const short8*)&w1ef[(size_t)(q * 128 + wave * 32 + tn * 16 + lm) * 8];
        #pragma unroll
        for (int tm = 0; tm < 4; tm++)
            afrag[tm] = *(const short8*)&abuf[(tm * 16 + lm) * 40 + q * 8];
        #pragma unroll
        for (int tm = 0; tm < 4; tm++)
            #pragma unroll
            for (int tn = 0; tn < 2; tn++)
                hacc[tm][tn] = __builtin_amdgcn_mfma_f32_16x16x32_bf16(afrag[tm], bfrag[tn], hacc[tm][tn], 0, 0, 0);
        // h = relu -> hbuf[pt][col]
        #pragma unroll
        for (int tm = 0; tm < 4; tm++)
            #pragma unroll
            for (int tn = 0; tn < 2; tn++) {
                int n2 = wave * 32 + tn * 16 + lm;
                #pragma unroll
                for (int r = 0; r < 4; r++) {
                    int m = tm * 16 + q * 4 + r;
                    hbuf[m * 136 + n2] = f2bf(fmaxf(hacc[tm][tn][r], 0.f));
                }
            }
    }
    __syncthreads();
    int n = wave * 16 + lm;    // each wave owns 16 comb cols
    // GEMM1: comb(64x64) = h(64x128) @ wcat(128x64)
    floatx4 acc[4];
    #pragma unroll
    for (int a = 0; a < 4; a++) acc[a] = (floatx4){0.f, 0.f, 0.f, 0.f};
    #pragma unroll
    for (int kk = 0; kk < 4; kk++) {
        short8 bfrag = *(const short8*)&wcatf[(size_t)((kk * 4 + q) * 64 + n) << 3];
        #pragma unroll
        for (int tm = 0; tm < 4; tm++) {
            short8 afrag = *(const short8*)&hbuf[(tm * 16 + lm) * 136 + kk * 32 + q * 8];
            acc[tm] = __builtin_amdgcn_mfma_f32_16x16x32_bf16(afrag, bfrag, acc[tm], 0, 0, 0);
        }
    }
    float bv = (n < 32) ? b2x[n] : b2r[n - 32];
    float comb_keep[4][4];
    #pragma unroll
    for (int tm = 0; tm < 4; tm++)
        #pragma unroll
        for (int r = 0; r < 4; r++) {
            float v = fmaxf(acc[tm][r] + bv, 0.f);
            comb_keep[tm][r] = v;
            int m = tm * 16 + q * 4 + r;     // C/D: row = quad*4+reg, col = lane&15
            cbuf[m * 72 + n] = f2bf(v);
        }
    __syncthreads();
    // GEMM2: att(64x64) = comb @ watt; same C-layout as comb -> register-local gating
    floatx4 acc2[4];
    #pragma unroll
    for (int a = 0; a < 4; a++) acc2[a] = (floatx4){0.f, 0.f, 0.f, 0.f};
    #pragma unroll
    for (int kk = 0; kk < 2; kk++) {
        short8 bfrag = *(const short8*)&wattf[(size_t)((kk * 4 + q) * 64 + n) << 3];
        #pragma unroll
        for (int tm = 0; tm < 4; tm++) {
            short8 afrag = *(const short8*)&cbuf[(tm * 16 + lm) * 72 + kk * 32 + q * 8];
            acc2[tm] = __builtin_amdgcn_mfma_f32_16x16x32_bf16(afrag, bfrag, acc2[tm], 0, 0, 0);
        }
    }
    float bv2 = (n < 32) ? bax[n] : bar[n - 32];
    int pp = (n < 32) ? n : 32 + n;   // pf2 col of plain value; gated at pp+32
    #pragma unroll
    for (int tm = 0; tm < 4; tm++)
        #pragma unroll
        for (int r = 0; r < 4; r++) {
            float att = acc2[tm][r] + bv2;
            float sg = 1.f / (1.f + __expf(-att));
            float plain = comb_keep[tm][r];
            float gated = plain * sg;
            int m = tm * 16 + q * 4 + r;
            hbuf[m * 136 + pp] = f2bf(plain);
            hbuf[m * 136 + pp + 32] = f2bf(gated);
        }
    __syncthreads();
    {   // coalesced pf2s store (sorted rows): 4 threads/row x 64B
        int row = t >> 2, seg = t & 3;
        if (row < mcnt) {
            const u16* src = &hbuf[row * 136 + seg * 32];
            u16* dst = pf2s + (size_t)(i0 + row) * 128 + seg * 32;
            *(uintx4*)dst = *(const uintx4*)src;
            *(uintx4*)(dst + 8) = *(const uintx4*)(src + 8);
        }
    }
    {   // fused segment-max -> voxmax fp32 (values >= 0; shifted-max form, int cmp)
        int c2 = t & 63;           // u32 col-pair (bf16 cols 2c2, 2c2+1) of 128
        int h = t >> 6;
        int r0 = h * 16;
        int r1 = r0 + 16; if (r1 > mcnt) r1 = mcnt;
        u32 mlo = 0, mhi = 0;
        int pvid = -1;
        for (int r = r0; r < r1; r++) {
            int vid = lvid[r];
            if (vid != pvid) {
                if (pvid >= 0) {
                    int* addr = (int*)(voxmax + (size_t)pvid * 128 + 2 * c2);
                    if (mlo) atomicMax(addr, (int)mlo);
                    if (mhi) atomicMax(addr + 1, (int)mhi);
                }
                pvid = vid; mlo = 0; mhi = 0;
            }
            u32 u = *(const u32*)&hbuf[r * 136 + 2 * c2];
            u32 lo = u << 16, hi = u & 0xffff0000u;
            mlo = lo > mlo ? lo : mlo;
            mhi = hi > mhi ? hi : mhi;
        }
        if (pvid >= 0) {
            int* addr = (int*)(voxmax + (size_t)pvid * 128 + 2 * c2);
            if (mlo) atomicMax(addr, (int)mlo);
            if (mhi) atomicMax(addr + 1, (int)mhi);
        }
    }
}

// ---- generic MFMA GEMM: out = relu(A @ W + bias); A fp32 or bf16; W pre-swizzled bf16 ----
template<int K, int N, bool ABF16, bool OUT_BF16>
__global__ __launch_bounds__(256) void k_gemm_relu(
    const void* __restrict__ Ap, const u16* __restrict__ Wf,
    const float* __restrict__ bias, void* __restrict__ outp, int M)
{
    constexpr int STRIDE = K + 8;
    constexpr int TN = N / 64;
    constexpr int KSTEPS = K / 32;
    constexpr int CW = K / 4;
    __shared__ u16 lds[64 * STRIDE];
    int i0 = blockIdx.x * 64;
    int mcnt = M - i0; if (mcnt > 64) mcnt = 64;
    int t = threadIdx.x;
    {
        int row = t >> 2, cseg = t & 3;
        u16* dst = &lds[row * STRIDE + cseg * CW];
        if (row < mcnt) {
            if (ABF16) {
                const u16* src = (const u16*)Ap + (size_t)(i0 + row) * K + cseg * CW;
                #pragma unroll
                for (int c = 0; c < CW / 8; c++)
                    *(uintx4*)(dst + c * 8) = *(const uintx4*)(src + c * 8);
            } else {
                const float* src = (const float*)Ap + (size_t)(i0 + row) * K + cseg * CW;
                #pragma unroll
                for (int c = 0; c < CW / 8; c++) {
                    float4 v0 = *(const float4*)(src + c * 8);
                    float4 v1 = *(const float4*)(src + c * 8 + 4);
                    uintx4 rr = {pkbf(v0.x, v0.y), pkbf(v0.z, v0.w), pkbf(v1.x, v1.y), pkbf(v1.z, v1.w)};
                    *(uintx4*)(dst + c * 8) = rr;
                }
            }
        } else {
            uintx4 z = {0, 0, 0, 0};
            #pragma unroll
            for (int c = 0; c < CW / 8; c++) *(uintx4*)(dst + c * 8) = z;
        }
    }
    __syncthreads();
    int wave = t >> 6, l = t & 63;
    int q = l >> 4, lm = l & 15;
    int wn0 = wave * (N / 4);
    floatx4 acc[4][TN];
    #pragma unroll
    for (int a = 0; a < 4; a++)
        #pragma unroll
        for (int b = 0; b < TN; b++) acc[a][b] = (floatx4){0.f, 0.f, 0.f, 0.f};
    #pragma unroll
    for (int kk = 0; kk < KSTEPS; kk++) {
        short8 afrag[4], bfrag[TN];
        #pragma unroll
        for (int tm = 0; tm < 4; tm++)
            afrag[tm] = *(const short8*)&lds[(tm * 16 + lm) * STRIDE + kk * 32 + q * 8];
        #pragma unroll
        for (int tn = 0; tn < TN; tn++)
            bfrag[tn] = *(const short8*)&Wf[(size_t)((kk * 4 + q) * N + wn0 + tn * 16 + lm) * 8];
        #pragma unroll
        for (int tm = 0; tm < 4; tm++)
            #pragma unroll
            for (int tn = 0; tn < TN; tn++)
                acc[tm][tn] = __builtin_amdgcn_mfma_f32_16x16x32_bf16(afrag[tm], bfrag[tn], acc[tm][tn], 0, 0, 0);
    }
    #pragma unroll
    for (int tm = 0; tm < 4; tm++)
        #pragma unroll
        for (int tn = 0; tn < TN; tn++) {
            int n = wn0 + tn * 16 + lm;
            float bv = bias[n];
            #pragma unroll
            for (int r = 0; r < 4; r++) {
                int m = tm * 16 + q * 4 + r;
                if (m < mcnt) {
                    float v = fmaxf(acc[tm][tn][r] + bv, 0.f);
                    if (OUT_BF16) ((u16*)outp)[(size_t)(i0 + m) * N + n] = f2bf(v);
                    else          ((float*)outp)[(size_t)(i0 + m) * N + n] = v;
                }
            }
        }
}

// ---- K3: sorted fused point MLP (swapped-operand MFMA) + in-LDS segmented max -> vox2 ----
// Both GEMMs transposed: D = W^T @ Act^T, weights A-operand (global), acts B-operand (LDS).
__global__ __launch_bounds__(256) void k_pointmlp(
    const u16* __restrict__ voxf, const u16* __restrict__ pf2s, const int* __restrict__ svid,
    const u16* __restrict__ w3f, const float* __restrict__ b3,
    const u16* __restrict__ w4f, const float* __restrict__ b4,
    float* __restrict__ vox2)
{
    constexpr int STRIDE = 264;
    __shared__ u16 lds[64 * STRIDE];
    __shared__ int lvid[64];
    __shared__ float bl[512];   // b3(256) | b4(256)
    int i0 = blockIdx.x * 64;
    int mcnt = NPTS - i0; if (mcnt > 64) mcnt = 64;
    int t = threadIdx.x;
    if (t < 64) lvid[t] = (t < mcnt) ? svid[i0 + t] : -1;
    for (int s = t; s < 512; s += 256) bl[s] = (s < 256) ? b3[s] : b4[s - 256];
    {
        int row = t >> 2, cseg = t & 3;       // 4 threads/row, 64 bf16 each
        u16* dst = &lds[row * STRIDE + cseg * 64];
        if (row < mcnt) {
            const u16* src;
            if (cseg < 2) src = voxf + (size_t)svid[i0 + row] * 128 + cseg * 64;     // pg half (sorted: locality)
            else          src = pf2s + (size_t)(i0 + row) * 128 + (cseg - 2) * 64;   // pf2 half (coalesced)
            #pragma unroll
            for (int c = 0; c < 8; c++)
                *(uintx4*)(dst + c * 8) = *(const uintx4*)(src + c * 8);
        } else {
            uintx4 z = {0, 0, 0, 0};
            #pragma unroll
            for (int c = 0; c < 8; c++) *(uintx4*)(dst + c * 8) = z;
        }
    }
    __syncthreads();
    int wave = t >> 6, l = t & 63;
    int q = l >> 4, lm = l & 15;
    int wm0 = wave * 64;     // wave's 64-wide output-channel stripe
    floatx4 acc[4][4];
    #pragma unroll
    for (int a = 0; a < 4; a++)
        #pragma unroll
        for (int b = 0; b < 4; b++) acc[a][b] = (floatx4){0.f, 0.f, 0.f, 0.f};
    #pragma unroll
    for (int kk = 0; kk < 8; kk++) {
        short8 wfrag[4], bfrag[4];
        #pragma unroll
        for (int tm = 0; tm < 4; tm++)
            wfrag[tm] = *(const short8*)&w3f[(size_t)((kk * 4 + q) * 256 + wm0 + tm * 16 + lm) * 8];
        #pragma unroll
        for (int tn = 0; tn < 4; tn++)
            bfrag[tn] = *(const short8*)&lds[(tn * 16 + lm) * STRIDE + kk * 32 + q * 8];
        #pragma unroll
        for (int tm = 0; tm < 4; tm++)
            #pragma unroll
            for (int tn = 0; tn < 4; tn++)
                acc[tm][tn] = __builtin_amdgcn_mfma_f32_16x16x32_bf16(wfrag[tm], bfrag[tn], acc[tm][tn], 0, 0, 0);
    }
    __syncthreads();
    // H = relu(acc + b3) -> LDS row-major, packed b64 (4 consecutive cols per frag)
    #pragma unroll
    for (int tm = 0; tm < 4; tm++) {
        float4 bq = *(const float4*)&bl[wm0 + tm * 16 + 4 * q];
        #pragma unroll
        for (int tn = 0; tn < 4; tn++) {
            u32 lo = pkbf(fmaxf(acc[tm][tn][0] + bq.x, 0.f), fmaxf(acc[tm][tn][1] + bq.y, 0.f));
            u32 hi = pkbf(fmaxf(acc[tm][tn][2] + bq.z, 0.f), fmaxf(acc[tm][tn][3] + bq.w, 0.f));
            *(uintx2*)&lds[(tn * 16 + lm) * STRIDE + wm0 + tm * 16 + 4 * q] = (uintx2){lo, hi};
        }
    }
    __syncthreads();
    floatx4 acc2[4][4];
    #pragma unroll
    for (int a = 0; a < 4; a++)
        #pragma unroll
        for (int b = 0; b < 4; b++) acc2[a][b] = (floatx4){0.f, 0.f, 0.f, 0.f};
    #pragma unroll
    for (int kk = 0; kk < 8; kk++) {
        short8 wfrag[4], bfrag[4];
        #pragma unroll
        for (int tm = 0; tm < 4; tm++)
            wfrag[tm] = *(const short8*)&w4f[(size_t)((kk * 4 + q) * 256 + wm0 + tm * 16 + lm) * 8];
        #pragma unroll
        for (int tn = 0; tn < 4; tn++)
            bfrag[tn] = *(const short8*)&lds[(tn * 16 + lm) * STRIDE + kk * 32 + q * 8];
        #pragma unroll
        for (int tm = 0; tm < 4; tm++)
            #pragma unroll
            for (int tn = 0; tn < 4; tn++)
                acc2[tm][tn] = __builtin_amdgcn_mfma_f32_16x16x32_bf16(wfrag[tm], bfrag[tn], acc2[tm][tn], 0, 0, 0);
    }
    __syncthreads();   // all waves done reading H before overwrite
    // pf5 = relu(acc2 + b4) -> LDS row-major, packed b64
    #pragma unroll
    for (int tm = 0; tm < 4; tm++) {
        float4 bq = *(const float4*)&bl[256 + wm0 + tm * 16 + 4 * q];
        #pragma unroll
        for (int tn = 0; tn < 4; tn++) {
            u32 lo = pkbf(fmaxf(acc2[tm][tn][0] + bq.x, 0.f), fmaxf(acc2[tm][tn][1] + bq.y, 0.f));
            u32 hi = pkbf(fmaxf(acc2[tm][tn][2] + bq.z, 0.f), fmaxf(acc2[tm][tn][3] + bq.w, 0.f));
            *(uintx2*)&lds[(tn * 16 + lm) * STRIDE + wm0 + tm * 16 + 4 * q] = (uintx2){lo, hi};
        }
    }
    __syncthreads();
    // segmented max: thread owns 4 bf16 channels (b64 col) x 16 rows; shifted-max form
    {
        int c4 = t & 63;           // uintx2 column (bf16 ch 4c4 .. 4c4+3)
        int g = t >> 6;            // 4 row-groups of 16
        int r0 = g * 16;
        int r1 = r0 + 16; if (r1 > mcnt) r1 = mcnt;
        u32 m0 = 0, m1 = 0, m2 = 0, m3 = 0;
        int pvid = -1;
        for (int r = r0; r < r1; r++) {
            int vid = lvid[r];
            if (vid != pvid) {
                if (pvid >= 0) {
                    int* addr = (int*)(vox2 + (size_t)pvid * 256 + 4 * c4);
                    if (m0) atomicMax(addr,     (int)m0);
                    if (m1) atomicMax(addr + 1, (int)m1);
                    if (m2) atomicMax(addr + 2, (int)m2);
                    if (m3) atomicMax(addr + 3, (int)m3);
                }
                pvid = vid; m0 = m1 = m2 = m3 = 0;
            }
            uintx2 u = *(const uintx2*)&lds[r * STRIDE + 4 * c4];
            u32 a0 = u[0] << 16, a1 = u[0] & 0xffff0000u;
            u32 a2 = u[1] << 16, a3 = u[1] & 0xffff0000u;
            m0 = a0 > m0 ? a0 : m0;
            m1 = a1 > m1 ? a1 : m1;
            m2 = a2 > m2 ? a2 : m2;
            m3 = a3 > m3 ? a3 : m3;
        }
        if (pvid >= 0) {
            int* addr = (int*)(vox2 + (size_t)pvid * 256 + 4 * c4);
            if (m0) atomicMax(addr,     (int)m0);
            if (m1) atomicMax(addr + 1, (int)m1);
            if (m2) atomicMax(addr + 2, (int)m2);
            if (m3) atomicMax(addr + 3, (int)m3);
        }
    }
}

extern "C" void kernel_launch(void* const* d_in, const int* in_sizes, int n_in,
                              void* d_out, int out_size, void* d_ws, size_t ws_size,
                              hipStream_t stream) {
    const float* inp = (const float*)d_in[0];
    const int*   idx = (const int*)d_in[1];
    const float* w1x = (const float*)d_in[3];  const float* b1x = (const float*)d_in[4];
    const float* w2x = (const float*)d_in[5];  const float* b2x = (const float*)d_in[6];
    const float* w1r = (const float*)d_in[7];  const float* b1r = (const float*)d_in[8];
    const float* w2r = (const float*)d_in[9];  const float* b2r = (const float*)d_in[10];
    const float* wax = (const float*)d_in[11]; const float* bax = (const float*)d_in[12];
    const float* war = (const float*)d_in[13]; const float* bar = (const float*)d_in[14];
    const float* wv1 = (const float*)d_in[15]; const float* bv1 = (const float*)d_in[16];
    const float* w3  = (const float*)d_in[17]; const float* b3  = (const float*)d_in[18];
    const float* w4  = (const float*)d_in[19]; const float* b4  = (const float*)d_in[20];
    const float* wv2 = (const float*)d_in[21]; const float* bv2 = (const float*)d_in[22];
    float* out = (float*)d_out;

    char* ws = (char*)d_ws;
    u16*   pf2s   = (u16*)ws;   ws += (size_t)NPTS * 128 * sizeof(u16);   // 128 MB (sorted rows)
    float* voxmax = (float*)ws; ws += (size_t)NVOX * 128 * sizeof(float); // 25.6 MB
    u16*   voxf   = (u16*)ws;   ws += (size_t)NVOX * 128 * sizeof(u16);   // 12.8 MB
    float* vox2   = (float*)ws; ws += (size_t)NVOX * 256 * sizeof(float); // 51.2 MB
    u16*   w3f    = (u16*)ws;   ws += 65536 * sizeof(u16);
    u16*   w4f    = (u16*)ws;   ws += 65536 * sizeof(u16);
    u16*   wv1f   = (u16*)ws;   ws += 16384 * sizeof(u16);
    u16*   wv2f   = (u16*)ws;   ws += 65536 * sizeof(u16);
    u16*   wcatf  = (u16*)ws;   ws += 8192 * sizeof(u16);
    u16*   wattf  = (u16*)ws;   ws += 4096 * sizeof(u16);
    u16*   w1ef   = (u16*)ws;   ws += 4096 * sizeof(u16);
    int*   hcnt   = (int*)ws;   ws += (size_t)NVOX * sizeof(int);
    int*   cur    = (int*)ws;   ws += (size_t)NVOX * sizeof(int);
    int*   bsum   = (int*)ws;   ws += (size_t)NBLK * sizeof(int);
    int*   boff   = (int*)ws;   ws += (size_t)NBLK * sizeof(int);
    int*   sptid  = (int*)ws;   ws += (size_t)NPTS * sizeof(int);
    int*   svid   = (int*)ws;   ws += (size_t)NPTS * sizeof(int);

    hipMemsetAsync(hcnt, 0, (size_t)NVOX * sizeof(int), stream);
    hipMemsetAsync(voxmax, 0, (size_t)NVOX * 128 * sizeof(float), stream);
    hipMemsetAsync(vox2, 0, (size_t)NVOX * 256 * sizeof(float), stream);

    k_wprep<<<896, 256, 0, stream>>>(w3, w4, wv1, wv2, w2x, w2r, wax, war,
                                     w1x, b1x, w1r, b1r,
                                     w3f, w4f, wv1f, wv2f, wcatf, wattf, w1ef);

    k_hist<<<(NPTS + 255) / 256, 256, 0, stream>>>(idx, hcnt);
    k_scan1<<<NBLK, 256, 0, stream>>>(hcnt, bsum);
    k_scan2<<<1, 256, 0, stream>>>(bsum, boff);
    k_scan3<<<NBLK, 256, 0, stream>>>(hcnt, boff, cur);
    k_scatter<<<(NPTS + 255) / 256, 256, 0, stream>>>(idx, cur, sptid, svid);

    k_pointfeat<<<(NPTS + 63) / 64, 256, 0, stream>>>(
        inp, sptid, svid, w1ef, wcatf, b2x, b2r, wattf, bax, bar, pf2s, voxmax);

    k_gemm_relu<128, 128, false, true><<<(NVOX + 63) / 64, 256, 0, stream>>>(
        (const void*)voxmax, wv1f, bv1, (void*)voxf, NVOX);

    k_pointmlp<<<(NPTS + 63) / 64, 256, 0, stream>>>(
        voxf, pf2s, svid, w3f, b3, w4f, b4, vox2);

    k_gemm_relu<256, 256, false, false><<<(NVOX + 63) / 64, 256, 0, stream>>>(
        (const void*)vox2, wv2f, bv2, (void*)out, NVOX);
}

// Round 9
// 506.194 us; speedup vs baseline: 1.1343x; 1.0785x over previous
//
#include <hip/hip_runtime.h>

#define NPTS 500000
#define NVOX 50000
#define NBLK 196   // ceil(NVOX/256)

typedef unsigned short u16;
typedef unsigned int u32;
typedef __attribute__((ext_vector_type(8))) short short8;
typedef __attribute__((ext_vector_type(4))) float floatx4;
typedef __attribute__((ext_vector_type(4))) unsigned int uintx4;
typedef __attribute__((ext_vector_type(2))) unsigned int uintx2;

__device__ __forceinline__ u16 f2bf(float f) {
    u32 u = __float_as_uint(f);
    u = u + 0x7fffu + ((u >> 16) & 1u);   // RNE
    return (u16)(u >> 16);
}

#if defined(__has_builtin)
#if __has_builtin(__builtin_amdgcn_cvt_pk_bf16_f32)
#define HAVE_PKBF 1
#endif
#endif

// pack two fp32 -> bf16x2 (a low, b high), RNE
__device__ __forceinline__ u32 pkbf(float a, float b) {
#ifdef HAVE_PKBF
    typedef __attribute__((ext_vector_type(2))) __bf16 bf16x2;
    bf16x2 v = __builtin_amdgcn_cvt_pk_bf16_f32(a, b);
    u32 r; __builtin_memcpy(&r, &v, 4);
    return r;
#else
    return (u32)f2bf(a) | ((u32)f2bf(b) << 16);
#endif
}

// ---- K0: all weight transforms fused. 16x16x32 pack (B-operand of W / A-operand of W^T):
//   Wf[((kk*4+q)*N + n)*8 + j] = W[(kk*32+q*8+j)*N + n]
__device__ __forceinline__ void wswz(const float* __restrict__ W, u16* __restrict__ Wf, int N, int t) {
    int k = t / N, n = t - k * N;
    int kk = k >> 5, q = (k >> 3) & 3, j = k & 7;
    Wf[((size_t)((kk * 4 + q) * N + n) << 3) + j] = f2bf(W[t]);
}

__global__ __launch_bounds__(256) void k_wprep(
    const float* __restrict__ w3, const float* __restrict__ w4,
    const float* __restrict__ wv1, const float* __restrict__ wv2,
    const float* __restrict__ w2x, const float* __restrict__ w2r,
    const float* __restrict__ wax, const float* __restrict__ war,
    const float* __restrict__ w1x, const float* __restrict__ b1x,
    const float* __restrict__ w1r, const float* __restrict__ b1r,
    u16* __restrict__ w3f, u16* __restrict__ w4f, u16* __restrict__ wv1f, u16* __restrict__ wv2f,
    u16* __restrict__ wcatf, u16* __restrict__ wattf, u16* __restrict__ w1ef)
{
    int t = blockIdx.x * 256 + threadIdx.x;
    if (t < 65536) { wswz(w3, w3f, 256, t); return; }  t -= 65536;
    if (t < 65536) { wswz(w4, w4f, 256, t); return; }  t -= 65536;
    if (t < 65536) { wswz(wv2, wv2f, 256, t); return; } t -= 65536;
    if (t < 16384) { wswz(wv1, wv1f, 128, t); return; } t -= 16384;
    if (t < 8192) {   // block-diag [[w2x,0],[0,w2r]] (128x64)
        int k = t >> 6, n = t & 63;
        float v;
        if (k < 64) v = (n < 32) ? w2x[k * 32 + n] : 0.f;
        else        v = (n >= 32) ? w2r[(k - 64) * 32 + (n - 32)] : 0.f;
        int kk = k >> 5, q = (k >> 3) & 3, j = k & 7;
        wcatf[((size_t)((kk * 4 + q) * 64 + n) << 3) + j] = f2bf(v);
        return;
    }
    t -= 8192;
    if (t < 4096) {   // [wax | war] (64x64)
        int k = t >> 6, n = t & 63;
        float v = (n < 32) ? wax[k * 32 + n] : war[k * 32 + (n - 32)];
        int kk = k >> 5, q = (k >> 3) & 3, j = k & 7;
        wattf[((size_t)((kk * 4 + q) * 64 + n) << 3) + j] = f2bf(v);
        return;
    }
    t -= 4096;
    if (t < 4096) {   // W1e (32x128): rows 0-2 w1x, 3 b1x (cols 0..63); 4-6 w1r, 7 b1r (cols 64..127)
        int k = t >> 7, n = t & 127;
        float v = 0.f;
        if (n < 64) {
            if (k < 3)       v = w1x[k * 64 + n];
            else if (k == 3) v = b1x[n];
        } else {
            if (k >= 4 && k < 7) v = w1r[(k - 4) * 64 + (n - 64)];
            else if (k == 7)     v = b1r[n - 64];
        }
        int q = (k >> 3) & 3, j = k & 7;   // kk = 0
        w1ef[((size_t)(q * 128 + n) << 3) + j] = f2bf(v);
    }
}

// ---- CSR build: histogram -> 3-phase parallel scan -> scatter (sptid + sorted vid) ----
__global__ void k_hist(const int* __restrict__ idx, int* __restrict__ hcnt) {
    int i = blockIdx.x * 256 + threadIdx.x;
    if (i < NPTS) atomicAdd(&hcnt[idx[i]], 1);
}

__global__ __launch_bounds__(256) void k_scan1(const int* __restrict__ hcnt, int* __restrict__ bsum) {
    __shared__ int wsum[4];
    int t = threadIdx.x;
    int i = blockIdx.x * 256 + t;
    int c = (i < NVOX) ? hcnt[i] : 0;
    #pragma unroll
    for (int d = 32; d >= 1; d >>= 1) c += __shfl_xor(c, d, 64);
    if ((t & 63) == 0) wsum[t >> 6] = c;
    __syncthreads();
    if (t == 0) bsum[blockIdx.x] = wsum[0] + wsum[1] + wsum[2] + wsum[3];
}

__global__ __launch_bounds__(256) void k_scan2(const int* __restrict__ bsum, int* __restrict__ boff) {
    __shared__ int wsum[4];
    int t = threadIdx.x, lane = t & 63, w = t >> 6;
    int c = (t < NBLK) ? bsum[t] : 0;
    int v = c;
    #pragma unroll
    for (int d = 1; d < 64; d <<= 1) {
        int o = __shfl_up(v, d, 64);
        if (lane >= d) v += o;
    }
    if (lane == 63) wsum[w] = v;
    __syncthreads();
    int wo = 0;
    #pragma unroll
    for (int k = 0; k < 4; k++) if (k < w) wo += wsum[k];
    if (t < NBLK) boff[t] = wo + v - c;
}

__global__ __launch_bounds__(256) void k_scan3(const int* __restrict__ hcnt, const int* __restrict__ boff,
                                               int* __restrict__ cur) {
    __shared__ int wsum[4];
    int t = threadIdx.x, lane = t & 63, w = t >> 6;
    int i = blockIdx.x * 256 + t;
    int c = (i < NVOX) ? hcnt[i] : 0;
    int v = c;
    #pragma unroll
    for (int d = 1; d < 64; d <<= 1) {
        int o = __shfl_up(v, d, 64);
        if (lane >= d) v += o;
    }
    if (lane == 63) wsum[w] = v;
    __syncthreads();
    int wo = 0;
    #pragma unroll
    for (int k = 0; k < 4; k++) if (k < w) wo += wsum[k];
    if (i < NVOX) cur[i] = boff[blockIdx.x] + wo + v - c;
}

__global__ void k_scatter(const int* __restrict__ idx, int* __restrict__ cur,
                          int* __restrict__ sptid, int* __restrict__ svid) {
    int i = blockIdx.x * 256 + threadIdx.x;
    if (i < NPTS) {
        int v = idx[i];
        int pos = atomicAdd(&cur[v], 1);
        sptid[pos] = i;
        svid[pos] = v;
    }
}

// ---- K1: sorted-order point encoder, ALL GEMMs swapped-operand (weights = A-operand),
// so every epilogue is packed b64 LDS writes. Fused segment-max -> voxmax (fp32).
__global__ __launch_bounds__(256) void k_pointfeat(
    const float* __restrict__ inp, const int* __restrict__ sptid, const int* __restrict__ svid,
    const u16* __restrict__ w1ef,
    const u16* __restrict__ wcatf, const float* __restrict__ b2x, const float* __restrict__ b2r,
    const u16* __restrict__ wattf, const float* __restrict__ bax, const float* __restrict__ bar,
    u16* __restrict__ pf2s, float* __restrict__ voxmax)
{
    __shared__ u16 hbuf[64 * 136];   // h tile [pt][ch] (64x128 +8 pad); reused for pf2 out-tile
    __shared__ u16 cbuf[64 * 72];    // comb tile [pt][ch] (64x64 +8 pad)
    __shared__ u16 abuf[64 * 40];    // layer-1 A tile [pt][k] (64x32 +8 pad)
    __shared__ float bl[128];        // [0..63] = [b2x|b2r], [64..127] = [bax|bar]
    __shared__ int lvid[64];
    int t = threadIdx.x;
    int i0 = blockIdx.x * 64;
    int mcnt = NPTS - i0; if (mcnt > 64) mcnt = 64;
    if (t < 64) lvid[t] = (t < mcnt) ? svid[i0 + t] : -1;
    else if (t < 128) { int s = t - 64;  bl[s] = (s < 32) ? b2x[s] : b2r[s - 32]; }
    else if (t < 192) { int s = t - 128; bl[64 + s] = (s < 32) ? bax[s] : bar[s - 32]; }
    {   // stage A rows: [x0,x1,x2,1, r0,r1,r2,1, 0 x24], 4 threads/point
        int m = t >> 2, c = t & 3;
        u16* ab = &abuf[m * 40];
        bool act = (m < mcnt);
        if (c < 3) {
            float2 v = {0.f, 0.f};
            if (act) v = *(const float2*)(inp + (size_t)sptid[i0 + m] * 6 + 2 * c);
            if (c == 0)      { ab[0] = f2bf(v.x); ab[1] = f2bf(v.y); }
            else if (c == 1) { ab[2] = f2bf(v.x); ab[4] = f2bf(v.y); }
            else             { ab[5] = f2bf(v.x); ab[6] = f2bf(v.y); }
        } else {
            u16 one = act ? (u16)0x3F80 : (u16)0;
            ab[3] = one; ab[7] = one;
        }
        #pragma unroll
        for (int z = 0; z < 3; z++) *(u32*)&ab[8 + 6 * c + 2 * z] = 0;   // zero cols 8..31
    }
    __syncthreads();
    int wave = t >> 6, l = t & 63, q = l >> 4, lm = l & 15;
    // GEMM_h swapped: h^T(128x64) = W1e^T @ A^T. Wave ch-stripe = wave*32 (tm in 0..1), all 64 pts.
    {
        floatx4 hacc[2][4];
        #pragma unroll
        for (int a = 0; a < 2; a++)
            #pragma unroll
            for (int b = 0; b < 4; b++) hacc[a][b] = (floatx4){0.f, 0.f, 0.f, 0.f};
        short8 wfrag[2], bfrag[4];
        #pragma unroll
        for (int tm = 0; tm < 2; tm++)
            wfrag[tm] = *(const short8*)&w1ef[(size_t)(q * 128 + wave * 32 + tm * 16 + lm) * 8];
        #pragma unroll
        for (int tn = 0; tn < 4; tn++)
            bfrag[tn] = *(const short8*)&abuf[(tn * 16 + lm) * 40 + q * 8];
        #pragma unroll
        for (int tm = 0; tm < 2; tm++)
            #pragma unroll
            for (int tn = 0; tn < 4; tn++)
                hacc[tm][tn] = __builtin_amdgcn_mfma_f32_16x16x32_bf16(wfrag[tm], bfrag[tn], hacc[tm][tn], 0, 0, 0);
        // h = relu -> hbuf[pt][ch], packed b64 (reg runs along ch)
        #pragma unroll
        for (int tm = 0; tm < 2; tm++) {
            int ch0 = wave * 32 + tm * 16 + 4 * q;
            #pragma unroll
            for (int tn = 0; tn < 4; tn++) {
                int pt = tn * 16 + lm;
                u32 lo = pkbf(fmaxf(hacc[tm][tn][0], 0.f), fmaxf(hacc[tm][tn][1], 0.f));
                u32 hi = pkbf(fmaxf(hacc[tm][tn][2], 0.f), fmaxf(hacc[tm][tn][3], 0.f));
                *(uintx2*)&hbuf[pt * 136 + ch0] = (uintx2){lo, hi};
            }
        }
    }
    __syncthreads();
    // GEMM1 swapped: comb^T(64x64) = wcat^T @ h^T. Wave ch-stripe = wave*16.
    floatx4 acc[4];
    #pragma unroll
    for (int a = 0; a < 4; a++) acc[a] = (floatx4){0.f, 0.f, 0.f, 0.f};
    #pragma unroll
    for (int kk = 0; kk < 4; kk++) {
        short8 wfrag = *(const short8*)&wcatf[(size_t)((kk * 4 + q) * 64 + wave * 16 + lm) * 8];
        #pragma unroll
        for (int tn = 0; tn < 4; tn++) {
            short8 bfrag = *(const short8*)&hbuf[(tn * 16 + lm) * 136 + kk * 32 + q * 8];
            acc[tn] = __builtin_amdgcn_mfma_f32_16x16x32_bf16(wfrag, bfrag, acc[tn], 0, 0, 0);
        }
    }
    int ch0 = wave * 16 + 4 * q;
    float4 bq = *(const float4*)&bl[ch0];
    float comb_keep[4][4];
    #pragma unroll
    for (int tn = 0; tn < 4; tn++) {
        int pt = tn * 16 + lm;
        float c0 = fmaxf(acc[tn][0] + bq.x, 0.f);
        float c1 = fmaxf(acc[tn][1] + bq.y, 0.f);
        float c2 = fmaxf(acc[tn][2] + bq.z, 0.f);
        float c3 = fmaxf(acc[tn][3] + bq.w, 0.f);
        comb_keep[tn][0] = c0; comb_keep[tn][1] = c1; comb_keep[tn][2] = c2; comb_keep[tn][3] = c3;
        *(uintx2*)&cbuf[pt * 72 + ch0] = (uintx2){pkbf(c0, c1), pkbf(c2, c3)};
    }
    __syncthreads();
    // GEMM2 swapped: att^T(64x64) = watt^T @ comb^T; same wave stripe -> register-local gating
    floatx4 acc2[4];
    #pragma unroll
    for (int a = 0; a < 4; a++) acc2[a] = (floatx4){0.f, 0.f, 0.f, 0.f};
    #pragma unroll
    for (int kk = 0; kk < 2; kk++) {
        short8 wfrag = *(const short8*)&wattf[(size_t)((kk * 4 + q) * 64 + wave * 16 + lm) * 8];
        #pragma unroll
        for (int tn = 0; tn < 4; tn++) {
            short8 bfrag = *(const short8*)&cbuf[(tn * 16 + lm) * 72 + kk * 32 + q * 8];
            acc2[tn] = __builtin_amdgcn_mfma_f32_16x16x32_bf16(wfrag, bfrag, acc2[tn], 0, 0, 0);
        }
    }
    float4 bq2 = *(const float4*)&bl[64 + ch0];
    int pp0 = (ch0 < 32) ? ch0 : 32 + ch0;   // pf2 col of plain quad; gated at pp0+32
    #pragma unroll
    for (int tn = 0; tn < 4; tn++) {
        int pt = tn * 16 + lm;
        float s0 = 1.f / (1.f + __expf(-(acc2[tn][0] + bq2.x)));
        float s1 = 1.f / (1.f + __expf(-(acc2[tn][1] + bq2.y)));
        float s2 = 1.f / (1.f + __expf(-(acc2[tn][2] + bq2.z)));
        float s3 = 1.f / (1.f + __expf(-(acc2[tn][3] + bq2.w)));
        float p0 = comb_keep[tn][0], p1 = comb_keep[tn][1], p2 = comb_keep[tn][2], p3 = comb_keep[tn][3];
        *(uintx2*)&hbuf[pt * 136 + pp0]      = (uintx2){pkbf(p0, p1), pkbf(p2, p3)};
        *(uintx2*)&hbuf[pt * 136 + pp0 + 32] = (uintx2){pkbf(p0 * s0, p1 * s1), pkbf(p2 * s2, p3 * s3)};
    }
    __syncthreads();
    {   // coalesced pf2s store (sorted rows): 4 threads/row x 64B
        int row = t >> 2, seg = t & 3;
        if (row < mcnt) {
            const u16* src = &hbuf[row * 136 + seg * 32];
            u16* dst = pf2s + (size_t)(i0 + row) * 128 + seg * 32;
            *(uintx4*)dst = *(const uintx4*)src;
            *(uintx4*)(dst + 8) = *(const uintx4*)(src + 8);
        }
    }
    {   // fused segment-max -> voxmax fp32 (values >= 0, int cmp); R5 form
        int c2 = t & 63;           // u32 col-pair (bf16 cols 2c2, 2c2+1) of 128
        int h = t >> 6;
        int r0 = h * 16;
        int r1 = r0 + 16; if (r1 > mcnt) r1 = mcnt;
        u32 mlo = 0, mhi = 0;
        int pvid = -1;
        for (int r = r0; r < r1; r++) {
            int vid = lvid[r];
            if (vid != pvid) {
                if (pvid >= 0) {
                    int* addr = (int*)(voxmax + (size_t)pvid * 128 + 2 * c2);
                    if (mlo) atomicMax(addr, (int)(mlo << 16));
                    if (mhi) atomicMax(addr + 1, (int)(mhi << 16));
                }
                pvid = vid; mlo = 0; mhi = 0;
            }
            u32 u = *(const u32*)&hbuf[r * 136 + 2 * c2];
            u32 lo = u & 0xffffu, hi = u >> 16;
            mlo = lo > mlo ? lo : mlo;
            mhi = hi > mhi ? hi : mhi;
        }
        if (pvid >= 0) {
            int* addr = (int*)(voxmax + (size_t)pvid * 128 + 2 * c2);
            if (mlo) atomicMax(addr, (int)(mlo << 16));
            if (mhi) atomicMax(addr + 1, (int)(mhi << 16));
        }
    }
}

// ---- generic MFMA GEMM: out = relu(A @ W + bias); A fp32 or bf16; W pre-swizzled bf16 ----
template<int K, int N, bool ABF16, bool OUT_BF16>
__global__ __launch_bounds__(256) void k_gemm_relu(
    const void* __restrict__ Ap, const u16* __restrict__ Wf,
    const float* __restrict__ bias, void* __restrict__ outp, int M)
{
    constexpr int STRIDE = K + 8;
    constexpr int TN = N / 64;
    constexpr int KSTEPS = K / 32;
    constexpr int CW = K / 4;
    __shared__ u16 lds[64 * STRIDE];
    int i0 = blockIdx.x * 64;
    int mcnt = M - i0; if (mcnt > 64) mcnt = 64;
    int t = threadIdx.x;
    {
        int row = t >> 2, cseg = t & 3;
        u16* dst = &lds[row * STRIDE + cseg * CW];
        if (row < mcnt) {
            if (ABF16) {
                const u16* src = (const u16*)Ap + (size_t)(i0 + row) * K + cseg * CW;
                #pragma unroll
                for (int c = 0; c < CW / 8; c++)
                    *(uintx4*)(dst + c * 8) = *(const uintx4*)(src + c * 8);
            } else {
                const float* src = (const float*)Ap + (size_t)(i0 + row) * K + cseg * CW;
                #pragma unroll
                for (int c = 0; c < CW / 8; c++) {
                    float4 v0 = *(const float4*)(src + c * 8);
                    float4 v1 = *(const float4*)(src + c * 8 + 4);
                    uintx4 rr = {pkbf(v0.x, v0.y), pkbf(v0.z, v0.w), pkbf(v1.x, v1.y), pkbf(v1.z, v1.w)};
                    *(uintx4*)(dst + c * 8) = rr;
                }
            }
        } else {
            uintx4 z = {0, 0, 0, 0};
            #pragma unroll
            for (int c = 0; c < CW / 8; c++) *(uintx4*)(dst + c * 8) = z;
        }
    }
    __syncthreads();
    int wave = t >> 6, l = t & 63;
    int q = l >> 4, lm = l & 15;
    int wn0 = wave * (N / 4);
    floatx4 acc[4][TN];
    #pragma unroll
    for (int a = 0; a < 4; a++)
        #pragma unroll
        for (int b = 0; b < TN; b++) acc[a][b] = (floatx4){0.f, 0.f, 0.f, 0.f};
    #pragma unroll
    for (int kk = 0; kk < KSTEPS; kk++) {
        short8 afrag[4], bfrag[TN];
        #pragma unroll
        for (int tm = 0; tm < 4; tm++)
            afrag[tm] = *(const short8*)&lds[(tm * 16 + lm) * STRIDE + kk * 32 + q * 8];
        #pragma unroll
        for (int tn = 0; tn < TN; tn++)
            bfrag[tn] = *(const short8*)&Wf[(size_t)((kk * 4 + q) * N + wn0 + tn * 16 + lm) * 8];
        #pragma unroll
        for (int tm = 0; tm < 4; tm++)
            #pragma unroll
            for (int tn = 0; tn < TN; tn++)
                acc[tm][tn] = __builtin_amdgcn_mfma_f32_16x16x32_bf16(afrag[tm], bfrag[tn], acc[tm][tn], 0, 0, 0);
    }
    #pragma unroll
    for (int tm = 0; tm < 4; tm++)
        #pragma unroll
        for (int tn = 0; tn < TN; tn++) {
            int n = wn0 + tn * 16 + lm;
            float bv = bias[n];
            #pragma unroll
            for (int r = 0; r < 4; r++) {
                int m = tm * 16 + q * 4 + r;
                if (m < mcnt) {
                    float v = fmaxf(acc[tm][tn][r] + bv, 0.f);
                    if (OUT_BF16) ((u16*)outp)[(size_t)(i0 + m) * N + n] = f2bf(v);
                    else          ((float*)outp)[(size_t)(i0 + m) * N + n] = v;
                }
            }
        }
}

// ---- K3: sorted fused point MLP (swapped-operand MFMA) + in-LDS segmented max -> vox2 ----
// Both GEMMs transposed: D = W^T @ Act^T, weights A-operand (global), acts B-operand (LDS).
__global__ __launch_bounds__(256) void k_pointmlp(
    const u16* __restrict__ voxf, const u16* __restrict__ pf2s, const int* __restrict__ svid,
    const u16* __restrict__ w3f, const float* __restrict__ b3,
    const u16* __restrict__ w4f, const float* __restrict__ b4,
    float* __restrict__ vox2)
{
    constexpr int STRIDE = 264;
    __shared__ u16 lds[64 * STRIDE];
    __shared__ int lvid[64];
    __shared__ float bl[512];   // b3(256) | b4(256)
    int i0 = blockIdx.x * 64;
    int mcnt = NPTS - i0; if (mcnt > 64) mcnt = 64;
    int t = threadIdx.x;
    if (t < 64) lvid[t] = (t < mcnt) ? svid[i0 + t] : -1;
    for (int s = t; s < 512; s += 256) bl[s] = (s < 256) ? b3[s] : b4[s - 256];
    {
        int row = t >> 2, cseg = t & 3;       // 4 threads/row, 64 bf16 each
        u16* dst = &lds[row * STRIDE + cseg * 64];
        if (row < mcnt) {
            const u16* src;
            if (cseg < 2) src = voxf + (size_t)svid[i0 + row] * 128 + cseg * 64;     // pg half (sorted: locality)
            else          src = pf2s + (size_t)(i0 + row) * 128 + (cseg - 2) * 64;   // pf2 half (coalesced)
            #pragma unroll
            for (int c = 0; c < 8; c++)
                *(uintx4*)(dst + c * 8) = *(const uintx4*)(src + c * 8);
        } else {
            uintx4 z = {0, 0, 0, 0};
            #pragma unroll
            for (int c = 0; c < 8; c++) *(uintx4*)(dst + c * 8) = z;
        }
    }
    __syncthreads();
    int wave = t >> 6, l = t & 63;
    int q = l >> 4, lm = l & 15;
    int wm0 = wave * 64;     // wave's 64-wide output-channel stripe
    floatx4 acc[4][4];
    #pragma unroll
    for (int a = 0; a < 4; a++)
        #pragma unroll
        for (int b = 0; b < 4; b++) acc[a][b] = (floatx4){0.f, 0.f, 0.f, 0.f};
    #pragma unroll
    for (int kk = 0; kk < 8; kk++) {
        short8 wfrag[4], bfrag[4];
        #pragma unroll
        for (int tm = 0; tm < 4; tm++)
            wfrag[tm] = *(const short8*)&w3f[(size_t)((kk * 4 + q) * 256 + wm0 + tm * 16 + lm) * 8];
        #pragma unroll
        for (int tn = 0; tn < 4; tn++)
            bfrag[tn] = *(const short8*)&lds[(tn * 16 + lm) * STRIDE + kk * 32 + q * 8];
        #pragma unroll
        for (int tm = 0; tm < 4; tm++)
            #pragma unroll
            for (int tn = 0; tn < 4; tn++)
                acc[tm][tn] = __builtin_amdgcn_mfma_f32_16x16x32_bf16(wfrag[tm], bfrag[tn], acc[tm][tn], 0, 0, 0);
    }
    __syncthreads();
    // H = relu(acc + b3) -> LDS row-major, packed b64 (4 consecutive cols per frag)
    #pragma unroll
    for (int tm = 0; tm < 4; tm++) {
        float4 bq = *(const float4*)&bl[wm0 + tm * 16 + 4 * q];
        #pragma unroll
        for (int tn = 0; tn < 4; tn++) {
            u32 lo = pkbf(fmaxf(acc[tm][tn][0] + bq.x, 0.f), fmaxf(acc[tm][tn][1] + bq.y, 0.f));
            u32 hi = pkbf(fmaxf(acc[tm][tn][2] + bq.z, 0.f), fmaxf(acc[tm][tn][3] + bq.w, 0.f));
            *(uintx2*)&lds[(tn * 16 + lm) * STRIDE + wm0 + tm * 16 + 4 * q] = (uintx2){lo, hi};
        }
    }
    __syncthreads();
    floatx4 acc2[4][4];
    #pragma unroll
    for (int a = 0; a < 4; a++)
        #pragma unroll
        for (int b = 0; b < 4; b++) acc2[a][b] = (floatx4){0.f, 0.f, 0.f, 0.f};
    #pragma unroll
    for (int kk = 0; kk < 8; kk++) {
        short8 wfrag[4], bfrag[4];
        #pragma unroll
        for (int tm = 0; tm < 4; tm++)
            wfrag[tm] = *(const short8*)&w4f[(size_t)((kk * 4 + q) * 256 + wm0 + tm * 16 + lm) * 8];
        #pragma unroll
        for (int tn = 0; tn < 4; tn++)
            bfrag[tn] = *(const short8*)&lds[(tn * 16 + lm) * STRIDE + kk * 32 + q * 8];
        #pragma unroll
        for (int tm = 0; tm < 4; tm++)
            #pragma unroll
            for (int tn = 0; tn < 4; tn++)
                acc2[tm][tn] = __builtin_amdgcn_mfma_f32_16x16x32_bf16(wfrag[tm], bfrag[tn], acc2[tm][tn], 0, 0, 0);
    }
    __syncthreads();   // all waves done reading H before overwrite
    // pf5 = relu(acc2 + b4) -> LDS row-major, packed b64
    #pragma unroll
    for (int tm = 0; tm < 4; tm++) {
        float4 bq = *(const float4*)&bl[256 + wm0 + tm * 16 + 4 * q];
        #pragma unroll
        for (int tn = 0; tn < 4; tn++) {
            u32 lo = pkbf(fmaxf(acc2[tm][tn][0] + bq.x, 0.f), fmaxf(acc2[tm][tn][1] + bq.y, 0.f));
            u32 hi = pkbf(fmaxf(acc2[tm][tn][2] + bq.z, 0.f), fmaxf(acc2[tm][tn][3] + bq.w, 0.f));
            *(uintx2*)&lds[(tn * 16 + lm) * STRIDE + wm0 + tm * 16 + 4 * q] = (uintx2){lo, hi};
        }
    }
    __syncthreads();
    // segmented max over sorted vid runs: thread owns u32 col-pair x 32 rows (R5 form)
    {
        int c2 = t & 127;          // u32 column (cols 2c2, 2c2+1)
        int h = t >> 7;            // row half
        int r0 = h * 32;
        int r1 = r0 + 32; if (r1 > mcnt) r1 = mcnt;
        u32 mlo = 0, mhi = 0;
        int pvid = -1;
        for (int r = r0; r < r1; r++) {
            int vid = lvid[r];
            if (vid != pvid) {
                if (pvid >= 0) {
                    int* addr = (int*)(vox2 + (size_t)pvid * 256 + 2 * c2);
                    if (mlo) atomicMax(addr, (int)(mlo << 16));
                    if (mhi) atomicMax(addr + 1, (int)(mhi << 16));
                }
                pvid = vid; mlo = 0; mhi = 0;
            }
            u32 u = *(const u32*)&lds[r * STRIDE + 2 * c2];
            u32 lo = u & 0xffffu, hi = u >> 16;
            mlo = lo > mlo ? lo : mlo;
            mhi = hi > mhi ? hi : mhi;
        }
        if (pvid >= 0) {
            int* addr = (int*)(vox2 + (size_t)pvid * 256 + 2 * c2);
            if (mlo) atomicMax(addr, (int)(mlo << 16));
            if (mhi) atomicMax(addr + 1, (int)(mhi << 16));
        }
    }
}

extern "C" void kernel_launch(void* const* d_in, const int* in_sizes, int n_in,
                              void* d_out, int out_size, void* d_ws, size_t ws_size,
                              hipStream_t stream) {
    const float* inp = (const float*)d_in[0];
    const int*   idx = (const int*)d_in[1];
    const float* w1x = (const float*)d_in[3];  const float* b1x = (const float*)d_in[4];
    const float* w2x = (const float*)d_in[5];  const float* b2x = (const float*)d_in[6];
    const float* w1r = (const float*)d_in[7];  const float* b1r = (const float*)d_in[8];
    const float* w2r = (const float*)d_in[9];  const float* b2r = (const float*)d_in[10];
    const float* wax = (const float*)d_in[11]; const float* bax = (const float*)d_in[12];
    const float* war = (const float*)d_in[13]; const float* bar = (const float*)d_in[14];
    const float* wv1 = (const float*)d_in[15]; const float* bv1 = (const float*)d_in[16];
    const float* w3  = (const float*)d_in[17]; const float* b3  = (const float*)d_in[18];
    const float* w4  = (const float*)d_in[19]; const float* b4  = (const float*)d_in[20];
    const float* wv2 = (const float*)d_in[21]; const float* bv2 = (const float*)d_in[22];
    float* out = (float*)d_out;

    char* ws = (char*)d_ws;
    u16*   pf2s   = (u16*)ws;   ws += (size_t)NPTS * 128 * sizeof(u16);   // 128 MB (sorted rows)
    float* voxmax = (float*)ws; ws += (size_t)NVOX * 128 * sizeof(float); // 25.6 MB
    u16*   voxf   = (u16*)ws;   ws += (size_t)NVOX * 128 * sizeof(u16);   // 12.8 MB
    float* vox2   = (float*)ws; ws += (size_t)NVOX * 256 * sizeof(float); // 51.2 MB
    u16*   w3f    = (u16*)ws;   ws += 65536 * sizeof(u16);
    u16*   w4f    = (u16*)ws;   ws += 65536 * sizeof(u16);
    u16*   wv1f   = (u16*)ws;   ws += 16384 * sizeof(u16);
    u16*   wv2f   = (u16*)ws;   ws += 65536 * sizeof(u16);
    u16*   wcatf  = (u16*)ws;   ws += 8192 * sizeof(u16);
    u16*   wattf  = (u16*)ws;   ws += 4096 * sizeof(u16);
    u16*   w1ef   = (u16*)ws;   ws += 4096 * sizeof(u16);
    int*   hcnt   = (int*)ws;   ws += (size_t)NVOX * sizeof(int);
    int*   cur    = (int*)ws;   ws += (size_t)NVOX * sizeof(int);
    int*   bsum   = (int*)ws;   ws += (size_t)NBLK * sizeof(int);
    int*   boff   = (int*)ws;   ws += (size_t)NBLK * sizeof(int);
    int*   sptid  = (int*)ws;   ws += (size_t)NPTS * sizeof(int);
    int*   svid   = (int*)ws;   ws += (size_t)NPTS * sizeof(int);

    hipMemsetAsync(hcnt, 0, (size_t)NVOX * sizeof(int), stream);
    hipMemsetAsync(voxmax, 0, (size_t)NVOX * 128 * sizeof(float), stream);
    hipMemsetAsync(vox2, 0, (size_t)NVOX * 256 * sizeof(float), stream);

    k_wprep<<<896, 256, 0, stream>>>(w3, w4, wv1, wv2, w2x, w2r, wax, war,
                                     w1x, b1x, w1r, b1r,
                                     w3f, w4f, wv1f, wv2f, wcatf, wattf, w1ef);

    k_hist<<<(NPTS + 255) / 256, 256, 0, stream>>>(idx, hcnt);
    k_scan1<<<NBLK, 256, 0, stream>>>(hcnt, bsum);
    k_scan2<<<1, 256, 0, stream>>>(bsum, boff);
    k_scan3<<<NBLK, 256, 0, stream>>>(hcnt, boff, cur);
    k_scatter<<<(NPTS + 255) / 256, 256, 0, stream>>>(idx, cur, sptid, svid);

    k_pointfeat<<<(NPTS + 63) / 64, 256, 0, stream>>>(
        inp, sptid, svid, w1ef, wcatf, b2x, b2r, wattf, bax, bar, pf2s, voxmax);

    k_gemm_relu<128, 128, false, true><<<(NVOX + 63) / 64, 256, 0, stream>>>(
        (const void*)voxmax, wv1f, bv1, (void*)voxf, NVOX);

    k_pointmlp<<<(NPTS + 63) / 64, 256, 0, stream>>>(
        voxf, pf2s, svid, w3f, b3, w4f, b4, vox2);

    k_gemm_relu<256, 256, false, false><<<(NVOX + 63) / 64, 256, 0, stream>>>(
        (const void*)vox2, wv2f, bv2, (void*)out, NVOX);
}